// Round 1
// baseline (97.286 us; speedup 1.0000x reference)
//
#include <hip/hip_runtime.h>
#include <hip/hip_bf16.h>

#ifndef __has_builtin
#define __has_builtin(x) 0
#endif

__device__ __forceinline__ float fast_exp2(float x) {
#if __has_builtin(__builtin_amdgcn_exp2f)
  return __builtin_amdgcn_exp2f(x);
#else
  return __exp2f(x);
#endif
}
__device__ __forceinline__ float fast_rcp(float x) {
#if __has_builtin(__builtin_amdgcn_rcpf)
  return __builtin_amdgcn_rcpf(x);
#else
  return 1.0f / x;
#endif
}

#define B_   16
#define NQ_  256
#define NK_  256
#define D_   256
#define QT   4
// tanh(x) = 1 - 2/(1 + exp2(x * 2*log2(e))); projections pre-scaled by this.
#define TANH_SCALE 2.8853900817779268f
#define LOG2E      1.4426950408889634f

// ---------------- projection GEMM (f32 vector ALU; no f32 MFMA on CDNA4) ----
// z=0: hqs = TANH_SCALE*(queries@Wq + b1)   [4096,256]
// z=1: hks = TANH_SCALE*(keys@Wk)           [4096,256]
__global__ __launch_bounds__(256) void proj_kernel(
    const float* __restrict__ queries, const float* __restrict__ keys,
    const float* __restrict__ Wq, const float* __restrict__ Wk,
    const float* __restrict__ b1,
    float* __restrict__ hqs, float* __restrict__ hks)
{
  const int z = blockIdx.z;
  const float* __restrict__ X = z ? keys : queries;
  const float* __restrict__ W = z ? Wk : Wq;
  float* __restrict__ O = z ? hks : hqs;

  const int m0 = blockIdx.x * 64;
  const int n0 = blockIdx.y * 64;
  const int t  = threadIdx.x;
  const int tx = t & 15, ty = t >> 4;

  __shared__ float As_t[64][68];  // [k][m], padded: (k*68+m)%32 varies with m
  __shared__ float Bs[64][68];    // [k][n]

  float acc[4][4] = {};

  for (int kt = 0; kt < 4; ++kt) {
    const int k0 = kt * 64;
    #pragma unroll
    for (int i = 0; i < 4; ++i) {          // A tile, stored transposed
      int f = t + 256 * i;
      int row = f >> 4;
      int kc  = (f & 15) << 2;
      float4 v = *(const float4*)&X[(size_t)(m0 + row) * D_ + (k0 + kc)];
      As_t[kc + 0][row] = v.x; As_t[kc + 1][row] = v.y;
      As_t[kc + 2][row] = v.z; As_t[kc + 3][row] = v.w;
    }
    #pragma unroll
    for (int i = 0; i < 4; ++i) {          // B tile
      int f = t + 256 * i;
      int kr = f >> 4;
      int nc = (f & 15) << 2;
      *(float4*)&Bs[kr][nc] = *(const float4*)&W[(size_t)(k0 + kr) * D_ + (n0 + nc)];
    }
    __syncthreads();
    #pragma unroll 8
    for (int k = 0; k < 64; ++k) {
      float4 a = *(const float4*)&As_t[k][ty << 2];
      float4 b = *(const float4*)&Bs[k][tx << 2];
      float aa[4] = {a.x, a.y, a.z, a.w};
      float bb[4] = {b.x, b.y, b.z, b.w};
      #pragma unroll
      for (int i = 0; i < 4; ++i)
        #pragma unroll
        for (int j = 0; j < 4; ++j)
          acc[i][j] = fmaf(aa[i], bb[j], acc[i][j]);
    }
    __syncthreads();
  }

  float bias[4] = {0.f, 0.f, 0.f, 0.f};
  if (z == 0) {
    #pragma unroll
    for (int j = 0; j < 4; ++j) bias[j] = b1[n0 + (tx << 2) + j];
  }
  #pragma unroll
  for (int i = 0; i < 4; ++i)
    #pragma unroll
    for (int j = 0; j < 4; ++j)
      O[(size_t)(m0 + (ty << 2) + i) * D_ + n0 + (tx << 2) + j] =
          TANH_SCALE * (acc[i][j] + bias[j]);
}

// ---------------- fused logits + softmax + PV ------------------------------
// Block = (b, 4 queries). Thread t = key index for logits, value index for PV.
// logit_eff = -2 * sum_d w2[d] * rcp(1 + exp2(hqs[d] + hks[d]))
// (constants sum(w2), b2 dropped: softmax is shift-invariant)
__global__ __launch_bounds__(256) void attn_kernel(
    const float* __restrict__ hqs, const float* __restrict__ hks,
    const float* __restrict__ values, const float* __restrict__ w2,
    float* __restrict__ out)
{
  const int q0 = blockIdx.x * QT;
  const int b  = blockIdx.y;
  const int t  = threadIdx.x;
  const int lane = t & 63, wave = t >> 6;

  __shared__ float hq4[D_][QT];    // [d][qi], float4-readable per d
  __shared__ float w2s[D_];
  __shared__ float attn4[NK_][QT];
  __shared__ float redA[4][QT], redB[4][QT];

  w2s[t] = w2[t];
  #pragma unroll
  for (int qi = 0; qi < QT; ++qi)
    hq4[t][qi] = hqs[(size_t)(b * NQ_ + q0 + qi) * D_ + t];
  __syncthreads();

  const float* __restrict__ hkrow = hks + (size_t)(b * NK_ + t) * D_;
  float acc[QT] = {};
  #pragma unroll 4
  for (int d4 = 0; d4 < D_ / 4; ++d4) {
    float4 hkv = *(const float4*)&hkrow[d4 << 2];
    float4 w2v = *(const float4*)&w2s[d4 << 2];
    float hk_a[4] = {hkv.x, hkv.y, hkv.z, hkv.w};
    float w2_a[4] = {w2v.x, w2v.y, w2v.z, w2v.w};
    #pragma unroll
    for (int j = 0; j < 4; ++j) {
      float4 hqv = *(const float4*)&hq4[(d4 << 2) + j][0];  // LDS broadcast
      float hq_a[4] = {hqv.x, hqv.y, hqv.z, hqv.w};
      #pragma unroll
      for (int qi = 0; qi < QT; ++qi) {
        float e = fast_exp2(hq_a[qi] + hk_a[j]);
        float r = fast_rcp(1.0f + e);
        acc[qi] = fmaf(w2_a[j], r, acc[qi]);
      }
    }
  }

  float logit[QT];
  #pragma unroll
  for (int qi = 0; qi < QT; ++qi) logit[qi] = -2.0f * acc[qi];

  // block-wide max per query row
  #pragma unroll
  for (int qi = 0; qi < QT; ++qi) {
    float v = logit[qi];
    #pragma unroll
    for (int off = 32; off; off >>= 1) v = fmaxf(v, __shfl_xor(v, off, 64));
    if (lane == 0) redA[wave][qi] = v;
  }
  __syncthreads();
  float mx[QT];
  #pragma unroll
  for (int qi = 0; qi < QT; ++qi)
    mx[qi] = fmaxf(fmaxf(redA[0][qi], redA[1][qi]),
                   fmaxf(redA[2][qi], redA[3][qi]));

  float p[QT];
  #pragma unroll
  for (int qi = 0; qi < QT; ++qi) {
    p[qi] = fast_exp2((logit[qi] - mx[qi]) * LOG2E);
    attn4[t][qi] = p[qi];
  }
  // block-wide sum per query row
  #pragma unroll
  for (int qi = 0; qi < QT; ++qi) {
    float v = p[qi];
    #pragma unroll
    for (int off = 32; off; off >>= 1) v += __shfl_xor(v, off, 64);
    if (lane == 0) redB[wave][qi] = v;
  }
  __syncthreads();
  float inv[QT];
  #pragma unroll
  for (int qi = 0; qi < QT; ++qi)
    inv[qi] = fast_rcp(redB[0][qi] + redB[1][qi] + redB[2][qi] + redB[3][qi]);

  // PV: thread t = value dim; coalesced values reads, attn broadcast from LDS
  float ctx[QT] = {};
  const float* __restrict__ vcol = values + (size_t)b * NK_ * D_ + t;
  #pragma unroll 4
  for (int k = 0; k < NK_; ++k) {
    float val = vcol[(size_t)k * D_];
    float4 av = *(const float4*)&attn4[k][0];
    float a_a[4] = {av.x, av.y, av.z, av.w};
    #pragma unroll
    for (int qi = 0; qi < QT; ++qi) ctx[qi] = fmaf(a_a[qi], val, ctx[qi]);
  }
  float* __restrict__ orow = out + (size_t)(b * NQ_ + q0) * D_ + t;
  #pragma unroll
  for (int qi = 0; qi < QT; ++qi) orow[(size_t)qi * D_] = ctx[qi] * inv[qi];
}

extern "C" void kernel_launch(void* const* d_in, const int* in_sizes, int n_in,
                              void* d_out, int out_size, void* d_ws, size_t ws_size,
                              hipStream_t stream)
{
  const float* keys    = (const float*)d_in[0];
  const float* queries = (const float*)d_in[1];
  const float* values  = (const float*)d_in[2];
  const float* Wk      = (const float*)d_in[3];
  const float* Wq      = (const float*)d_in[4];
  const float* b1      = (const float*)d_in[5];
  const float* w2      = (const float*)d_in[6];
  // d_in[7] = b2: dropped (softmax shift-invariance)

  float* hqs = (float*)d_ws;                       // [4096,256] f32, 4 MB
  float* hks = hqs + (size_t)B_ * NQ_ * D_;        // [4096,256] f32, 4 MB
  float* out = (float*)d_out;

  dim3 pgrid(B_ * NQ_ / 64, D_ / 64, 2);           // 64 x 4 x 2 = 512 blocks
  proj_kernel<<<pgrid, 256, 0, stream>>>(queries, keys, Wq, Wk, b1, hqs, hks);

  dim3 agrid(NQ_ / QT, B_);                        // 64 x 16 = 1024 blocks
  attn_kernel<<<agrid, 256, 0, stream>>>(hqs, hks, values, w2, out);
}